// Round 1
// baseline (762.129 us; speedup 1.0000x reference)
//
#include <hip/hip_runtime.h>

#define IN_C   256
#define OUT_C  512
#define WIDTH  56
#define HW     3136        // 56*56
#define KTAPS  9
#define KTOT   2304        // IN_C*9
#define NF     64
#define NB     32
#define BK     32          // K-step
#define LDK    40          // padded LDS row stride in bf16 elems (80 B, 16B-aligned chunks)

typedef __bf16 bf16x8 __attribute__((ext_vector_type(8)));
typedef float  f32x4  __attribute__((ext_vector_type(4)));

// ---------------- kernel 1: global average pool ----------------
// grid = B*IN_C blocks, 256 threads; block (b,c) reduces 3136 contiguous floats
__global__ __launch_bounds__(256) void pool_kernel(const float* __restrict__ x,
                                                   float* __restrict__ pooled) {
    int bc = blockIdx.x;
    const float* src = x + (size_t)bc * HW;
    float s = 0.f;
    for (int i = threadIdx.x; i < HW; i += 256) s += src[i];
    #pragma unroll
    for (int off = 32; off > 0; off >>= 1) s += __shfl_down(s, off, 64);
    __shared__ float wsum[4];
    int lane = threadIdx.x & 63, wv = threadIdx.x >> 6;
    if (lane == 0) wsum[wv] = s;
    __syncthreads();
    if (threadIdx.x == 0)
        pooled[bc] = (wsum[0] + wsum[1] + wsum[2] + wsum[3]) * (1.0f / HW);
}

// ---------------- kernel 2: router GEMV + top-64 selection ----------------
// grid = B blocks, 512 threads (one per out channel)
__global__ __launch_bounds__(512) void router_kernel(const float* __restrict__ pooled,
                                                     const float* __restrict__ rw,
                                                     const float* __restrict__ rb,
                                                     int* __restrict__ sel) {
    int b = blockIdx.x;
    __shared__ float p[IN_C];
    __shared__ float v[OUT_C];
    __shared__ int   flag[OUT_C];
    int t = threadIdx.x;
    if (t < IN_C) p[t] = pooled[b * IN_C + t];
    __syncthreads();
    float acc = rb[t];
    const float* wrow = rw + (size_t)t * IN_C;
    for (int i = 0; i < IN_C; ++i) acc += p[i] * wrow[i];
    v[t] = acc;
    __syncthreads();
    // stable rank: count of strictly-greater, plus equal-with-lower-index
    int cnt = 0;
    for (int j = 0; j < OUT_C; ++j) {
        float o = v[j];
        cnt += (o > acc) || (o == acc && j < t);
    }
    flag[t] = (cnt < NF) ? 1 : 0;
    __syncthreads();
    if (t == 0) {
        int pos = 0;
        for (int j = 0; j < OUT_C; ++j)
            if (flag[j]) sel[b * NF + (pos++)] = j;
    }
}

// ---------------- kernel 3: sparse conv as implicit GEMM (bf16 MFMA) ----------------
// grid = (49 pixel-tiles, 32 batches), 256 threads = 4 waves.
// Block tile: M=64 selected ocs x N=64 pixels, K-loop over 2304 in steps of 32.
// Wave wv owns M-rows [16wv,16wv+16), 4 accumulators of 16x16.
__global__ __launch_bounds__(256) void conv_kernel(const float* __restrict__ x,
                                                   const float* __restrict__ w,
                                                   const float* __restrict__ bias,
                                                   const int* __restrict__ sel,
                                                   float* __restrict__ out) {
    int b     = blockIdx.y;
    int ptile = blockIdx.x * 64;
    int t     = threadIdx.x;
    int lane  = t & 63, wv = t >> 6;

    __shared__ __bf16 Alds[64 * LDK];
    __shared__ __bf16 Blds[64 * LDK];
    __shared__ int    t_off[KTOT];   // ic*HW + (r-1)*56 + (c-1)
    __shared__ short  t_rc[KTOT];    // r | (c<<8)

    // build k-decomposition table (wave-uniform broadcast reads later)
    for (int k = t; k < KTOT; k += 256) {
        int ic  = k / 9;
        int rem = k - ic * 9;
        int r   = rem / 3;
        int c   = rem - r * 3;
        t_off[k] = ic * HW + (r - 1) * WIDTH + (c - 1);
        t_rc[k]  = (short)(r | (c << 8));
    }

    // A staging: thread -> (oc_l = t>>2, kchunk = t&3), 8 consecutive k's
    int a_oc = t >> 2, a_kc = t & 3;
    int a_sel = sel[b * NF + a_oc];
    const float* a_src = w + (size_t)a_sel * KTOT + a_kc * 8;
    __bf16* a_dst = &Alds[a_oc * LDK + a_kc * 8];

    // B staging: thread -> (kchunk = wave, px = lane): coalesced x loads, wave-uniform k
    int b_px = lane, b_kc = wv;
    int p  = ptile + b_px;
    int oh = p / WIDTH, ow = p - (p / WIDTH) * WIDTH;
    const float* x_bp = x + (size_t)b * IN_C * HW + p;
    __bf16* b_dst = &Blds[b_px * LDK + b_kc * 8];

    // fragment read pointers (fixed across K-loop; LDS rewritten each step)
    int fm = lane & 15, fq = lane >> 4;
    const __bf16* a_frag_p = &Alds[(wv * 16 + fm) * LDK + fq * 8];
    const __bf16* b_frag_p = &Blds[fm * LDK + fq * 8];

    f32x4 acc[4] = {};

    for (int ks = 0; ks < KTOT; ks += BK) {
        __syncthreads();   // also covers table init on first iteration
        // ---- stage A tile: 64 oc x 32 k ----
        {
            float4 w0 = *(const float4*)(a_src + ks);
            float4 w1 = *(const float4*)(a_src + ks + 4);
            bf16x8 v8;
            v8[0] = (__bf16)w0.x; v8[1] = (__bf16)w0.y;
            v8[2] = (__bf16)w0.z; v8[3] = (__bf16)w0.w;
            v8[4] = (__bf16)w1.x; v8[5] = (__bf16)w1.y;
            v8[6] = (__bf16)w1.z; v8[7] = (__bf16)w1.w;
            *(bf16x8*)a_dst = v8;
        }
        // ---- stage B tile (im2col gather): 32 k x 64 px ----
        {
            bf16x8 v8;
            #pragma unroll
            for (int j = 0; j < 8; ++j) {
                int k   = ks + b_kc * 8 + j;
                int off = t_off[k];
                int rc  = t_rc[k];
                int r = rc & 255, c = rc >> 8;
                float val = 0.f;
                if ((unsigned)(oh + r - 1) < 56u && (unsigned)(ow + c - 1) < 56u)
                    val = x_bp[off];
                v8[j] = (__bf16)val;
            }
            *(bf16x8*)b_dst = v8;
        }
        __syncthreads();
        // ---- MFMA: wave computes its 16 rows x 64 px ----
        bf16x8 af = *(const bf16x8*)a_frag_p;
        #pragma unroll
        for (int s = 0; s < 4; ++s) {
            bf16x8 bfr = *(const bf16x8*)(b_frag_p + s * 16 * LDK);
            acc[s] = __builtin_amdgcn_mfma_f32_16x16x32_bf16(af, bfr, acc[s], 0, 0, 0);
        }
    }

    // ---- epilogue: bias add + store. C/D: col=lane&15 (px), row=fq*4+reg (oc) ----
    size_t out_b = (size_t)b * OUT_C * HW;
    #pragma unroll
    for (int reg = 0; reg < 4; ++reg) {
        int m  = wv * 16 + fq * 4 + reg;
        int oc = sel[b * NF + m];
        float bs = bias[oc];
        float* orow = out + out_b + (size_t)oc * HW + ptile + fm;
        #pragma unroll
        for (int s = 0; s < 4; ++s)
            orow[s * 16] = acc[s][reg] + bs;
    }
}

extern "C" void kernel_launch(void* const* d_in, const int* in_sizes, int n_in,
                              void* d_out, int out_size, void* d_ws, size_t ws_size,
                              hipStream_t stream) {
    (void)in_sizes; (void)n_in; (void)ws_size;
    const float* x        = (const float*)d_in[0];
    const float* weight   = (const float*)d_in[1];
    const float* bias     = (const float*)d_in[2];
    const float* router_w = (const float*)d_in[3];
    const float* router_b = (const float*)d_in[4];
    float* out = (float*)d_out;

    float* pooled = (float*)d_ws;                                  // 32*256 f32 = 32 KB
    int*   sel    = (int*)((char*)d_ws + NB * IN_C * sizeof(float)); // 32*64 int = 8 KB

    // unselected planes are exactly zero (mask multiplies bias too)
    hipMemsetAsync(d_out, 0, (size_t)out_size * sizeof(float), stream);

    pool_kernel<<<NB * IN_C, 256, 0, stream>>>(x, pooled);
    router_kernel<<<NB, OUT_C, 0, stream>>>(pooled, router_w, router_b, sel);

    dim3 grid(HW / 64, NB);   // 49 x 32
    conv_kernel<<<grid, 256, 0, stream>>>(x, weight, bias, sel, out);
}

// Round 2
// 405.529 us; speedup vs baseline: 1.8793x; 1.8793x over previous
//
#include <hip/hip_runtime.h>

#define IN_C   256
#define OUT_C  512
#define WIDTH  56
#define HW     3136        // 56*56
#define KTOT   2304        // IN_C*9
#define NF     64
#define NB     32
#define NGRP   8           // ic groups of 32
#define TN     128         // pixels per block
#define NTILE  25          // ceil(3136/128)
#define XROWS  242         // TN + 2*57 halo
#define LDX    40          // padded LDS row stride (bf16 elems) = 80 B

typedef __bf16 bf16x8 __attribute__((ext_vector_type(8)));
typedef float  f32x4  __attribute__((ext_vector_type(4)));

// ---------------- kernel 1: global average pool ----------------
__global__ __launch_bounds__(256) void pool_kernel(const float* __restrict__ x,
                                                   float* __restrict__ pooled) {
    int bc = blockIdx.x;
    const float* src = x + (size_t)bc * HW;
    float s = 0.f;
    for (int i = threadIdx.x; i < HW; i += 256) s += src[i];
    #pragma unroll
    for (int off = 32; off > 0; off >>= 1) s += __shfl_down(s, off, 64);
    __shared__ float wsum[4];
    int lane = threadIdx.x & 63, wv = threadIdx.x >> 6;
    if (lane == 0) wsum[wv] = s;
    __syncthreads();
    if (threadIdx.x == 0)
        pooled[bc] = (wsum[0] + wsum[1] + wsum[2] + wsum[3]) * (1.0f / HW);
}

// ---------------- kernel 2: router GEMV + top-64 selection ----------------
__global__ __launch_bounds__(512) void router_kernel(const float* __restrict__ pooled,
                                                     const float* __restrict__ rw,
                                                     const float* __restrict__ rb,
                                                     int* __restrict__ sel,
                                                     int* __restrict__ selflag) {
    int b = blockIdx.x;
    __shared__ float p[IN_C];
    __shared__ float v[OUT_C];
    __shared__ int   scount;
    int t = threadIdx.x;
    if (t < IN_C) p[t] = pooled[b * IN_C + t];
    if (t == 0) scount = 0;
    __syncthreads();
    float acc = rb[t];
    const float* wrow = rw + (size_t)t * IN_C;
    for (int i = 0; i < IN_C; ++i) acc += p[i] * wrow[i];
    v[t] = acc;
    __syncthreads();
    // stable rank: count strictly-greater, plus equal-with-lower-index (matches top_k tie rule)
    int cnt = 0;
    for (int j = 0; j < OUT_C; ++j) {
        float o = v[j];
        cnt += (o > acc) || (o == acc && j < t);
    }
    int is_sel = (cnt < NF) ? 1 : 0;
    selflag[b * OUT_C + t] = is_sel;
    if (is_sel) {
        int pos = atomicAdd(&scount, 1);   // order irrelevant: we scatter by oc
        sel[b * NF + pos] = t;
    }
}

// ---------------- kernel 3: weight compaction into MFMA-A fragment layout ----------------
// Acomp[((b*8+g)*9+tap)*64 + oc][32 icl] bf16. blockIdx = b*72 + g*9 + tap.
__global__ __launch_bounds__(256) void compact_w(const float* __restrict__ w,
                                                 const int* __restrict__ sel,
                                                 __bf16* __restrict__ Acomp) {
    int id = blockIdx.x;
    int b = id / 72, rem = id - b * 72;
    int g = rem / 9, tap = rem - g * 9;
    int t = threadIdx.x;
    int oc = t >> 2, q = t & 3;
    int s = sel[b * NF + oc];
    const float* wsrc = w + (size_t)s * KTOT + tap;   // + ic*9
    bf16x8 o;
    #pragma unroll
    for (int j = 0; j < 8; ++j)
        o[j] = (__bf16)wsrc[(g * 32 + q * 8 + j) * 9];
    *(bf16x8*)&Acomp[((size_t)id * 64 + oc) * 32 + q * 8] = o;
}

// ---------------- kernel 4: zero only unselected output planes ----------------
__global__ __launch_bounds__(256) void zero_unselected(const int* __restrict__ selflag,
                                                       float* __restrict__ out) {
    int bc = blockIdx.x;
    if (selflag[bc]) return;   // conv writes this plane fully
    float4* dst = (float4*)(out + (size_t)bc * HW);
    float4 z = {0.f, 0.f, 0.f, 0.f};
    for (int i = threadIdx.x; i < HW / 4; i += 256) dst[i] = z;
}

// ---------------- kernel 5: sparse conv, halo-tile + 9-tap MFMA ----------------
// grid = (25 px-tiles, 32 batches), 256 threads = 4 waves.
// Block: M=64 selected ocs x N=128 px. Wave: M32 x N64 (8 acc frags).
// K-loop: 8 ic-groups of 32; per group one LDS x-slab (242 px x 32 ic) serves 9 taps.
__global__ __launch_bounds__(256, 4) void conv_kernel(const float* __restrict__ x,
                                                      const __bf16* __restrict__ Acomp,
                                                      const float* __restrict__ bias,
                                                      const int* __restrict__ sel,
                                                      float* __restrict__ out) {
    int b     = blockIdx.y;
    int ptile = blockIdx.x * TN;
    int t     = threadIdx.x;
    int lane  = t & 63, wv = t >> 6;
    int fm    = lane & 15, fq = lane >> 4;
    int m_base = (wv & 1) * 32;
    int n_base = (wv >> 1) * 64;

    __shared__ __bf16 xlds[2][XROWS * LDX];

    const float*  x_b    = x + (size_t)b * IN_C * HW;
    const __bf16* a_base = Acomp + (size_t)b * (NGRP * 9 * 64 * 32);

    // per-s output pixel coords (fixed for whole kernel)
    int pp[4], poh[4], pow_[4];
    #pragma unroll
    for (int s = 0; s < 4; ++s) {
        int p = ptile + n_base + s * 16 + fm;
        pp[s] = p;
        int pc = p < HW ? p : HW - 1;          // only store-masked lanes clamp
        poh[s]  = pc / WIDTH;
        pow_[s] = pc - poh[s] * WIDTH;
    }

    // staging: thread t == px_e row (242 active), 32 ic scalar loads per group
    int  sp   = t;
    bool sact = sp < XROWS;
    int  gp   = ptile - 57 + sp;
    gp = gp < 0 ? 0 : (gp > HW - 1 ? HW - 1 : gp);  // clamped; consumers mask invalids
    const float* sx = x_b + gp;

    // prologue: stage group 0 into buf 0
    if (sact) {
        #pragma unroll
        for (int oct = 0; oct < 4; ++oct) {
            float v[8];
            #pragma unroll
            for (int j = 0; j < 8; ++j) v[j] = sx[(size_t)(oct * 8 + j) * HW];
            bf16x8 o;
            #pragma unroll
            for (int j = 0; j < 8; ++j) o[j] = (__bf16)v[j];
            *(bf16x8*)&xlds[0][sp * LDX + oct * 8] = o;
        }
    }
    __syncthreads();

    f32x4 acc[2][4] = {};
    float pre[32];

    for (int g = 0; g < NGRP; ++g) {
        int cur = g & 1;
        // (a) issue next group's global loads (latency hidden under tap loop)
        if (g < NGRP - 1 && sact) {
            #pragma unroll
            for (int i = 0; i < 32; ++i)
                pre[i] = sx[(size_t)((g + 1) * 32 + i) * HW];
        }
        // (b) 9 taps from the staged slab
        const __bf16* ap = a_base + (size_t)g * 9 * 64 * 32;
        #pragma unroll
        for (int t9 = 0; t9 < 9; ++t9) {
            const int r = t9 / 3, c = t9 - 3 * (t9 / 3);
            const int shift = (r - 1) * WIDTH + (c - 1);
            bf16x8 af0 = *(const bf16x8*)(ap + ((size_t)(t9 * 64 + m_base + fm)) * 32 + fq * 8);
            bf16x8 af1 = *(const bf16x8*)(ap + ((size_t)(t9 * 64 + m_base + 16 + fm)) * 32 + fq * 8);
            #pragma unroll
            for (int s = 0; s < 4; ++s) {
                int ohr = poh[s] + r - 1, owc = pow_[s] + c - 1;
                bool ok = ((unsigned)ohr < 56u) && ((unsigned)owc < 56u);
                int n = n_base + s * 16 + fm;
                bf16x8 bfr = *(const bf16x8*)&xlds[cur][(n + 57 + shift) * LDX + fq * 8];
                bf16x8 z = {};
                bfr = ok ? bfr : z;
                acc[0][s] = __builtin_amdgcn_mfma_f32_16x16x32_bf16(af0, bfr, acc[0][s], 0, 0, 0);
                acc[1][s] = __builtin_amdgcn_mfma_f32_16x16x32_bf16(af1, bfr, acc[1][s], 0, 0, 0);
            }
        }
        // (c) convert + write next slab to the other buffer, one barrier per group
        if (g < NGRP - 1) {
            if (sact) {
                #pragma unroll
                for (int oct = 0; oct < 4; ++oct) {
                    bf16x8 o;
                    #pragma unroll
                    for (int j = 0; j < 8; ++j) o[j] = (__bf16)pre[oct * 8 + j];
                    *(bf16x8*)&xlds[cur ^ 1][sp * LDX + oct * 8] = o;
                }
            }
            __syncthreads();
        }
    }

    // epilogue: bias + masked store. C/D: col(lane&15)=px, row=fq*4+reg=oc-slot
    const int* selb = sel + b * NF;
    size_t outb = (size_t)b * OUT_C * HW;
    #pragma unroll
    for (int i = 0; i < 2; ++i) {
        #pragma unroll
        for (int reg = 0; reg < 4; ++reg) {
            int m  = m_base + i * 16 + fq * 4 + reg;
            int oc = selb[m];
            float bs = bias[oc];
            float* orow = out + outb + (size_t)oc * HW;
            #pragma unroll
            for (int s = 0; s < 4; ++s)
                if (pp[s] < HW) orow[pp[s]] = acc[i][s][reg] + bs;
        }
    }
}

extern "C" void kernel_launch(void* const* d_in, const int* in_sizes, int n_in,
                              void* d_out, int out_size, void* d_ws, size_t ws_size,
                              hipStream_t stream) {
    (void)in_sizes; (void)n_in; (void)ws_size; (void)out_size;
    const float* x        = (const float*)d_in[0];
    const float* weight   = (const float*)d_in[1];
    const float* bias     = (const float*)d_in[2];
    const float* router_w = (const float*)d_in[3];
    const float* router_b = (const float*)d_in[4];
    float* out = (float*)d_out;

    char* ws = (char*)d_ws;
    float*  pooled  = (float*)ws;                      // 32 KB
    int*    sel     = (int*)(ws + 32768);              // 8 KB
    int*    selflag = (int*)(ws + 40960);              // 64 KB
    __bf16* Acomp   = (__bf16*)(ws + 131072);          // 9.44 MB

    pool_kernel<<<NB * IN_C, 256, 0, stream>>>(x, pooled);
    router_kernel<<<NB, OUT_C, 0, stream>>>(pooled, router_w, router_b, sel, selflag);
    compact_w<<<NB * NGRP * 9, 256, 0, stream>>>(weight, sel, Acomp);
    zero_unselected<<<NB * OUT_C, 256, 0, stream>>>(selflag, out);

    dim3 grid(NTILE, NB);   // 25 x 32
    conv_kernel<<<grid, 256, 0, stream>>>(x, Acomp, bias, sel, out);
}